// Round 7
// baseline (166.153 us; speedup 1.0000x reference)
//
#include <hip/hip_runtime.h>
#include <math.h>

#define NSITES 100000
#define NYEARS 20
#define HDIM 64

typedef __bf16 bf16x8 __attribute__((ext_vector_type(8)));
typedef float f32x4 __attribute__((ext_vector_type(4)));

__device__ __forceinline__ float sigmoidf_(float x) { return 1.0f / (1.0f + __expf(-x)); }
__device__ __forceinline__ float eluf_(float x) { return x > 0.0f ? x : expm1f(x); }

// load 8 consecutive f32 (32B-aligned) -> bf16x8 (RNE via __bf16 cast)
__device__ __forceinline__ bf16x8 cvt8_(const float* p) {
    float4 a = ((const float4*)p)[0];
    float4 b = ((const float4*)p)[1];
    bf16x8 r;
    r[0] = (__bf16)a.x; r[1] = (__bf16)a.y; r[2] = (__bf16)a.z; r[3] = (__bf16)a.w;
    r[4] = (__bf16)b.x; r[5] = (__bf16)b.y; r[6] = (__bf16)b.z; r[7] = (__bf16)b.w;
    return r;
}

__device__ __forceinline__ bf16x8 pack_bf_(f32x4 lo, f32x4 hi) {
    bf16x8 r;
    r[0] = (__bf16)lo[0]; r[1] = (__bf16)lo[1]; r[2] = (__bf16)lo[2]; r[3] = (__bf16)lo[3];
    r[4] = (__bf16)hi[0]; r[5] = (__bf16)hi[1]; r[6] = (__bf16)hi[2]; r[7] = (__bf16)hi[3];
    return r;
}

// One wave = 16 sites. Permuted-output-row MFMA recurrence (validated R5/R6):
//   pi(32kt+8q+4b+r)=16(2kt+b)+4q+r  => lane's D regs ARE its next B-fragment.
// R7 changes vs R6:
//  * G=1 again (6250 waves = 6.1/SIMD of TLP)
//  * t-loop ROLLED (#pragma unroll 1): body ~2KB, L1I-resident (R5/R6's fully
//    unrolled ~50KB body thrashed the 32KB I-cache -> ~1500cyc/round stalls)
//  * __launch_bounds__(64,4): 128-reg budget -> 4 waves/SIMD residency.
//    To fit: xs staged in LDS (broadcast ds_read/round), bias folded into
//    first MFMA's C operand, a_hh loaded after the h0 stage.
__global__ __launch_bounds__(64, 4)
void rnet_kernel(const float* __restrict__ sxy0,
                 const float* __restrict__ sxy,
                 const float* __restrict__ oxy,
                 const float* __restrict__ W_h0, const float* __restrict__ b_h0,
                 const float* __restrict__ W_h1, const float* __restrict__ b_h1,
                 const float* __restrict__ W_ih, const float* __restrict__ b_ih,
                 const float* __restrict__ W_hh, const float* __restrict__ b_hh,
                 const float* __restrict__ W_psi0, const float* __restrict__ b_psi0,
                 const float* __restrict__ W_psi, const float* __restrict__ b_psi,
                 const float* __restrict__ W_p, const float* __restrict__ b_p,
                 float* __restrict__ out)
{
    const int lane = threadIdx.x;       // 0..63
    const int s = lane & 15;            // site within wave / A-row within tile
    const int q = lane >> 4;            // quad
    const int sq = s >> 2, sr = s & 3;
    const int base = blockIdx.x * 16;   // NSITES = 6250*16 exactly
    const int site = base + s;

    __shared__ __align__(16) float xs_sh[16 * 19];    // per-site x values
    __shared__ __align__(16) float pL_sh[16 * 20];    // p logit of h_j at [site][j]
    __shared__ __align__(16) float psiL_sh[16 * 20];  // psi logit of h_j at [site][j] (slot 0 unused)
    __shared__ __align__(16) float psi0L_sh[16];      // psi0 logit of h0

    float* __restrict__ out_psi0 = out;                 // [N]
    float* __restrict__ out_psi  = out + NSITES;        // [N,19]
    float* __restrict__ out_p    = out + 20 * NSITES;   // [N,20,2]

    // ---- stage xs: 304 contiguous floats, coalesced ----
    {
        const float* src = sxy + (size_t)base * (NYEARS - 1);
#pragma unroll
        for (int r = 0; r < 5; ++r) {
            int i = r * 64 + lane;
            if (i < 16 * (NYEARS - 1)) xs_sh[i] = src[i];
        }
    }

    // ---- h0 stage: hs = elu(s0*W_h0+b_h0) in B layout; h0 via permuted W_h1 ----
    bf16x8 bf[2];
    {
        const float s0v = sxy0[site];
        bf16x8 bf0[2];
#pragma unroll
        for (int kt = 0; kt < 2; ++kt) {
            const float* wp = W_h0 + kt * 32 + q * 8;
            const float* bp = b_h0 + kt * 32 + q * 8;
            float4 w0 = ((const float4*)wp)[0], w1 = ((const float4*)wp)[1];
            float4 c0 = ((const float4*)bp)[0], c1 = ((const float4*)bp)[1];
            float v[8];
            v[0] = eluf_(fmaf(s0v, w0.x, c0.x)); v[1] = eluf_(fmaf(s0v, w0.y, c0.y));
            v[2] = eluf_(fmaf(s0v, w0.z, c0.z)); v[3] = eluf_(fmaf(s0v, w0.w, c0.w));
            v[4] = eluf_(fmaf(s0v, w1.x, c1.x)); v[5] = eluf_(fmaf(s0v, w1.y, c1.y));
            v[6] = eluf_(fmaf(s0v, w1.z, c1.z)); v[7] = eluf_(fmaf(s0v, w1.w, c1.w));
#pragma unroll
            for (int j = 0; j < 8; ++j) bf0[kt][j] = (__bf16)v[j];
        }

        f32x4 acc[4];
#pragma unroll
        for (int mt = 0; mt < 4; ++mt) {
            const int dr = 32 * (mt >> 1) + 8 * q + 4 * (mt & 1);
            float4 b1 = *(const float4*)(b_h1 + dr);
            acc[mt][0] = b1.x; acc[mt][1] = b1.y; acc[mt][2] = b1.z; acc[mt][3] = b1.w;
        }
#pragma unroll
        for (int kt = 0; kt < 2; ++kt)
#pragma unroll
            for (int mt = 0; mt < 4; ++mt) {
                const int ar = 32 * (mt >> 1) + 8 * sq + 4 * (mt & 1) + sr;
                bf16x8 a = cvt8_(W_h1 + ar * 64 + kt * 32 + q * 8);
                acc[mt] = __builtin_amdgcn_mfma_f32_16x16x32_bf16(a, bf0[kt], acc[mt], 0, 0, 0);
            }
        f32x4 e[4];
#pragma unroll
        for (int mt = 0; mt < 4; ++mt)
#pragma unroll
            for (int r = 0; r < 4; ++r) e[mt][r] = eluf_(acc[mt][r]);
        bf[0] = pack_bf_(e[0], e[1]);
        bf[1] = pack_bf_(e[2], e[3]);
    }

    // ---- persistent loop state (loaded after h0 to cap peak pressure) ----
    bf16x8 a_hh[4][2];
#pragma unroll
    for (int mt = 0; mt < 4; ++mt) {
        const int ar = 32 * (mt >> 1) + 8 * sq + 4 * (mt & 1) + sr;
#pragma unroll
        for (int kt = 0; kt < 2; ++kt)
            a_hh[mt][kt] = cvt8_(W_hh + ar * 64 + kt * 32 + q * 8);
    }
    bf16x8 a_head[2];
    {
        const float* hrow = (s == 1) ? W_p : ((s == 2) ? W_psi0 : W_psi);
#pragma unroll
        for (int kt = 0; kt < 2; ++kt) a_head[kt] = cvt8_(hrow + kt * 32 + q * 8);
    }
    f32x4 biasD[4], wihD[4];
#pragma unroll
    for (int mt = 0; mt < 4; ++mt) {
        const int dr = 32 * (mt >> 1) + 8 * q + 4 * (mt & 1);
        float4 bi = *(const float4*)(b_ih + dr);
        float4 bh = *(const float4*)(b_hh + dr);
        float4 wi = *(const float4*)(W_ih + dr);
        biasD[mt][0] = bi.x + bh.x; biasD[mt][1] = bi.y + bh.y;
        biasD[mt][2] = bi.z + bh.z; biasD[mt][3] = bi.w + bh.w;
        wihD[mt][0] = wi.x; wihD[mt][1] = wi.y; wihD[mt][2] = wi.z; wihD[mt][3] = wi.w;
    }
    f32x4 headC;
    headC[0] = (q == 0) ? b_psi[0]  : 0.0f;
    headC[1] = (q == 0) ? b_p[0]    : 0.0f;
    headC[2] = (q == 0) ? b_psi0[0] : 0.0f;
    headC[3] = 0.0f;

    // ---- recurrence: ROLLED. Round t: bf = h_{t-1} -> heads(h_{t-1}), h_t ----
#pragma unroll 1
    for (int t = 1; t < NYEARS; ++t) {
        const float x = xs_sh[s * 19 + (t - 1)];   // broadcast within quad, conflict-free

        // bias folded into first MFMA's C operand
        f32x4 acc[4], accH;
#pragma unroll
        for (int mt = 0; mt < 4; ++mt)
            acc[mt] = __builtin_amdgcn_mfma_f32_16x16x32_bf16(a_hh[mt][0], bf[0], biasD[mt], 0, 0, 0);
        accH = __builtin_amdgcn_mfma_f32_16x16x32_bf16(a_head[0], bf[0], headC, 0, 0, 0);
#pragma unroll
        for (int mt = 0; mt < 4; ++mt)
            acc[mt] = __builtin_amdgcn_mfma_f32_16x16x32_bf16(a_hh[mt][1], bf[1], acc[mt], 0, 0, 0);
        accH = __builtin_amdgcn_mfma_f32_16x16x32_bf16(a_head[1], bf[1], accH, 0, 0, 0);

        f32x4 hn[4];
#pragma unroll
        for (int mt = 0; mt < 4; ++mt)
#pragma unroll
            for (int r = 0; r < 4; ++r)
                hn[mt][r] = fmaxf(fmaf(x, wihD[mt][r], acc[mt][r]), 0.0f);
        bf[0] = pack_bf_(hn[0], hn[1]);
        bf[1] = pack_bf_(hn[2], hn[3]);

        if (q == 0) {
            // accH over h_{t-1}: [0]=psi logit, [1]=p logit, [2]=psi0 logit
            pL_sh[s * 20 + (t - 1)]   = accH[1];
            psiL_sh[s * 20 + (t - 1)] = accH[0];
            if (t == 1) psi0L_sh[s] = accH[2];
        }
    }

    // ---- final heads on h_19 ----
    {
        f32x4 accH = __builtin_amdgcn_mfma_f32_16x16x32_bf16(a_head[0], bf[0], headC, 0, 0, 0);
        accH = __builtin_amdgcn_mfma_f32_16x16x32_bf16(a_head[1], bf[1], accH, 0, 0, 0);
        if (q == 0) {
            pL_sh[s * 20 + 19]   = accH[1];
            psiL_sh[s * 20 + 19] = accH[0];
        }
    }

    __syncthreads();

    // ---- epilogue: sigmoid + oxy, coalesced ----
    const float wpo = W_p[HDIM];
    // psi0
    if (lane < 16) out_psi0[base + lane] = sigmoidf_(psi0L_sh[lane]);
    // psi: out flat i = site_local*19 + c  <-  psiL_sh[site_local*20 + c + 1]
#pragma unroll
    for (int r = 0; r < 5; ++r) {
        int i = r * 64 + lane;
        if (i < 16 * 19) {
            int sl = i / 19, c = i - sl * 19;
            out_psi[(size_t)base * 19 + i] = sigmoidf_(psiL_sh[sl * 20 + c + 1]);
        }
    }
    // p: 16*40 = 640 floats = 160 float4; float idx f -> logit pL_sh[f>>1]
    const float4* oxy_b = (const float4*)(oxy + (size_t)base * 40);
    float4* outp_b = (float4*)(out_p + (size_t)base * 40);
#pragma unroll
    for (int r = 0; r < 3; ++r) {
        int i4 = r * 64 + lane;
        if (i4 < 160) {
            float4 ox = oxy_b[i4];
            float lg0 = pL_sh[i4 * 2];
            float lg1 = pL_sh[i4 * 2 + 1];
            float4 pv;
            pv.x = sigmoidf_(fmaf(wpo, ox.x, lg0));
            pv.y = sigmoidf_(fmaf(wpo, ox.y, lg0));
            pv.z = sigmoidf_(fmaf(wpo, ox.z, lg1));
            pv.w = sigmoidf_(fmaf(wpo, ox.w, lg1));
            outp_b[i4] = pv;
        }
    }
}

extern "C" void kernel_launch(void* const* d_in, const int* in_sizes, int n_in,
                              void* d_out, int out_size, void* d_ws, size_t ws_size,
                              hipStream_t stream) {
    const float* sxy0   = (const float*)d_in[0];
    const float* sxy    = (const float*)d_in[1];
    const float* oxy    = (const float*)d_in[2];
    const float* W_h0   = (const float*)d_in[3];
    const float* b_h0   = (const float*)d_in[4];
    const float* W_h1   = (const float*)d_in[5];
    const float* b_h1   = (const float*)d_in[6];
    const float* W_ih   = (const float*)d_in[7];
    const float* b_ih   = (const float*)d_in[8];
    const float* W_hh   = (const float*)d_in[9];
    const float* b_hh   = (const float*)d_in[10];
    const float* W_psi0 = (const float*)d_in[11];
    const float* b_psi0 = (const float*)d_in[12];
    const float* W_psi  = (const float*)d_in[13];
    const float* b_psi  = (const float*)d_in[14];
    const float* W_p    = (const float*)d_in[15];
    const float* b_p    = (const float*)d_in[16];

    float* out = (float*)d_out;

    dim3 block(64);
    dim3 grid(NSITES / 16);   // 6250 waves, 16 sites each
    rnet_kernel<<<grid, block, 0, stream>>>(
        sxy0, sxy, oxy, W_h0, b_h0, W_h1, b_h1, W_ih, b_ih, W_hh, b_hh,
        W_psi0, b_psi0, W_psi, b_psi, W_p, b_p, out);
}

// Round 8
// 149.172 us; speedup vs baseline: 1.1138x; 1.1138x over previous
//
#include <hip/hip_runtime.h>
#include <math.h>

#define NSITES 100000
#define NYEARS 20
#define HDIM 64

typedef __bf16 bf16x8 __attribute__((ext_vector_type(8)));
typedef float f32x4 __attribute__((ext_vector_type(4)));

__device__ __forceinline__ float sigmoidf_(float x) { return 1.0f / (1.0f + __expf(-x)); }
__device__ __forceinline__ float eluf_(float x) { return x > 0.0f ? x : expm1f(x); }

// load 8 consecutive f32 (32B-aligned) -> bf16x8 (RNE via __bf16 cast)
__device__ __forceinline__ bf16x8 cvt8_(const float* p) {
    float4 a = ((const float4*)p)[0];
    float4 b = ((const float4*)p)[1];
    bf16x8 r;
    r[0] = (__bf16)a.x; r[1] = (__bf16)a.y; r[2] = (__bf16)a.z; r[3] = (__bf16)a.w;
    r[4] = (__bf16)b.x; r[5] = (__bf16)b.y; r[6] = (__bf16)b.z; r[7] = (__bf16)b.w;
    return r;
}

__device__ __forceinline__ bf16x8 pack_bf_(f32x4 lo, f32x4 hi) {
    bf16x8 r;
    r[0] = (__bf16)lo[0]; r[1] = (__bf16)lo[1]; r[2] = (__bf16)lo[2]; r[3] = (__bf16)lo[3];
    r[4] = (__bf16)hi[0]; r[5] = (__bf16)hi[1]; r[6] = (__bf16)hi[2]; r[7] = (__bf16)hi[3];
    return r;
}

// One wave = 16 sites. Permuted-output-row MFMA recurrence (validated R5-R7):
//   pi(32kt+8q+4b+r)=16(2kt+b)+4q+r  => lane's D regs ARE its next B-fragment.
// R8: rolled t-loop (L1I-resident ~800B body; R5/R6's 18-36KB unrolled bodies
// were I-fetch-bandwidth bound) + __launch_bounds__(64,3): 170-reg unified
// budget fits the ~160-reg loop state (R7's (64,4)=128 budget spilled 23
// regs/lane -> 37.5MB scratch writes). 3 waves/SIMD residency.
__global__ __launch_bounds__(64, 3)
void rnet_kernel(const float* __restrict__ sxy0,
                 const float* __restrict__ sxy,
                 const float* __restrict__ oxy,
                 const float* __restrict__ W_h0, const float* __restrict__ b_h0,
                 const float* __restrict__ W_h1, const float* __restrict__ b_h1,
                 const float* __restrict__ W_ih, const float* __restrict__ b_ih,
                 const float* __restrict__ W_hh, const float* __restrict__ b_hh,
                 const float* __restrict__ W_psi0, const float* __restrict__ b_psi0,
                 const float* __restrict__ W_psi, const float* __restrict__ b_psi,
                 const float* __restrict__ W_p, const float* __restrict__ b_p,
                 float* __restrict__ out)
{
    const int lane = threadIdx.x;       // 0..63
    const int s = lane & 15;            // site within wave / A-row within tile
    const int q = lane >> 4;            // quad
    const int sq = s >> 2, sr = s & 3;
    const int base = blockIdx.x * 16;   // NSITES = 6250*16 exactly
    const int site = base + s;

    __shared__ __align__(16) float xs_sh[16 * 19];    // per-site x values
    __shared__ __align__(16) float pL_sh[16 * 20];    // p logit of h_j at [site][j]
    __shared__ __align__(16) float psiL_sh[16 * 20];  // psi logit of h_j (slot 0 unused)
    __shared__ __align__(16) float psi0L_sh[16];      // psi0 logit of h0

    float* __restrict__ out_psi0 = out;                 // [N]
    float* __restrict__ out_psi  = out + NSITES;        // [N,19]
    float* __restrict__ out_p    = out + 20 * NSITES;   // [N,20,2]

    // ---- stage xs: 304 contiguous floats, coalesced ----
    {
        const float* src = sxy + (size_t)base * (NYEARS - 1);
#pragma unroll
        for (int r = 0; r < 5; ++r) {
            int i = r * 64 + lane;
            if (i < 16 * (NYEARS - 1)) xs_sh[i] = src[i];
        }
    }

    // ---- h0 stage: hs = elu(s0*W_h0+b_h0) in B layout; h0 via permuted W_h1 ----
    bf16x8 bf[2];
    {
        const float s0v = sxy0[site];
        bf16x8 bf0[2];
#pragma unroll
        for (int kt = 0; kt < 2; ++kt) {
            const float* wp = W_h0 + kt * 32 + q * 8;
            const float* bp = b_h0 + kt * 32 + q * 8;
            float4 w0 = ((const float4*)wp)[0], w1 = ((const float4*)wp)[1];
            float4 c0 = ((const float4*)bp)[0], c1 = ((const float4*)bp)[1];
            float v[8];
            v[0] = eluf_(fmaf(s0v, w0.x, c0.x)); v[1] = eluf_(fmaf(s0v, w0.y, c0.y));
            v[2] = eluf_(fmaf(s0v, w0.z, c0.z)); v[3] = eluf_(fmaf(s0v, w0.w, c0.w));
            v[4] = eluf_(fmaf(s0v, w1.x, c1.x)); v[5] = eluf_(fmaf(s0v, w1.y, c1.y));
            v[6] = eluf_(fmaf(s0v, w1.z, c1.z)); v[7] = eluf_(fmaf(s0v, w1.w, c1.w));
#pragma unroll
            for (int j = 0; j < 8; ++j) bf0[kt][j] = (__bf16)v[j];
        }

        f32x4 acc[4];
#pragma unroll
        for (int mt = 0; mt < 4; ++mt) {
            const int dr = 32 * (mt >> 1) + 8 * q + 4 * (mt & 1);
            float4 b1 = *(const float4*)(b_h1 + dr);
            acc[mt][0] = b1.x; acc[mt][1] = b1.y; acc[mt][2] = b1.z; acc[mt][3] = b1.w;
        }
#pragma unroll
        for (int kt = 0; kt < 2; ++kt)
#pragma unroll
            for (int mt = 0; mt < 4; ++mt) {
                const int ar = 32 * (mt >> 1) + 8 * sq + 4 * (mt & 1) + sr;
                bf16x8 a = cvt8_(W_h1 + ar * 64 + kt * 32 + q * 8);
                acc[mt] = __builtin_amdgcn_mfma_f32_16x16x32_bf16(a, bf0[kt], acc[mt], 0, 0, 0);
            }
        f32x4 e[4];
#pragma unroll
        for (int mt = 0; mt < 4; ++mt)
#pragma unroll
            for (int r = 0; r < 4; ++r) e[mt][r] = eluf_(acc[mt][r]);
        bf[0] = pack_bf_(e[0], e[1]);
        bf[1] = pack_bf_(e[2], e[3]);
    }

    // ---- persistent loop state (loaded after h0 to cap peak pressure) ----
    bf16x8 a_hh[4][2];
#pragma unroll
    for (int mt = 0; mt < 4; ++mt) {
        const int ar = 32 * (mt >> 1) + 8 * sq + 4 * (mt & 1) + sr;
#pragma unroll
        for (int kt = 0; kt < 2; ++kt)
            a_hh[mt][kt] = cvt8_(W_hh + ar * 64 + kt * 32 + q * 8);
    }
    bf16x8 a_head[2];
    {
        const float* hrow = (s == 1) ? W_p : ((s == 2) ? W_psi0 : W_psi);
#pragma unroll
        for (int kt = 0; kt < 2; ++kt) a_head[kt] = cvt8_(hrow + kt * 32 + q * 8);
    }
    f32x4 biasD[4], wihD[4];
#pragma unroll
    for (int mt = 0; mt < 4; ++mt) {
        const int dr = 32 * (mt >> 1) + 8 * q + 4 * (mt & 1);
        float4 bi = *(const float4*)(b_ih + dr);
        float4 bh = *(const float4*)(b_hh + dr);
        float4 wi = *(const float4*)(W_ih + dr);
        biasD[mt][0] = bi.x + bh.x; biasD[mt][1] = bi.y + bh.y;
        biasD[mt][2] = bi.z + bh.z; biasD[mt][3] = bi.w + bh.w;
        wihD[mt][0] = wi.x; wihD[mt][1] = wi.y; wihD[mt][2] = wi.z; wihD[mt][3] = wi.w;
    }
    f32x4 headC;
    headC[0] = (q == 0) ? b_psi[0]  : 0.0f;
    headC[1] = (q == 0) ? b_p[0]    : 0.0f;
    headC[2] = (q == 0) ? b_psi0[0] : 0.0f;
    headC[3] = 0.0f;

    // ---- recurrence: ROLLED. Round t: bf = h_{t-1} -> heads(h_{t-1}), h_t ----
#pragma unroll 1
    for (int t = 1; t < NYEARS; ++t) {
        const float x = xs_sh[s * 19 + (t - 1)];   // broadcast within quad

        f32x4 acc[4], accH;
#pragma unroll
        for (int mt = 0; mt < 4; ++mt)
            acc[mt] = __builtin_amdgcn_mfma_f32_16x16x32_bf16(a_hh[mt][0], bf[0], biasD[mt], 0, 0, 0);
        accH = __builtin_amdgcn_mfma_f32_16x16x32_bf16(a_head[0], bf[0], headC, 0, 0, 0);
#pragma unroll
        for (int mt = 0; mt < 4; ++mt)
            acc[mt] = __builtin_amdgcn_mfma_f32_16x16x32_bf16(a_hh[mt][1], bf[1], acc[mt], 0, 0, 0);
        accH = __builtin_amdgcn_mfma_f32_16x16x32_bf16(a_head[1], bf[1], accH, 0, 0, 0);

        f32x4 hn[4];
#pragma unroll
        for (int mt = 0; mt < 4; ++mt)
#pragma unroll
            for (int r = 0; r < 4; ++r)
                hn[mt][r] = fmaxf(fmaf(x, wihD[mt][r], acc[mt][r]), 0.0f);
        bf[0] = pack_bf_(hn[0], hn[1]);
        bf[1] = pack_bf_(hn[2], hn[3]);

        if (q == 0) {
            // accH over h_{t-1}: [0]=psi logit, [1]=p logit, [2]=psi0 logit
            pL_sh[s * 20 + (t - 1)]   = accH[1];
            psiL_sh[s * 20 + (t - 1)] = accH[0];
            if (t == 1) psi0L_sh[s] = accH[2];
        }
    }

    // ---- final heads on h_19 ----
    {
        f32x4 accH = __builtin_amdgcn_mfma_f32_16x16x32_bf16(a_head[0], bf[0], headC, 0, 0, 0);
        accH = __builtin_amdgcn_mfma_f32_16x16x32_bf16(a_head[1], bf[1], accH, 0, 0, 0);
        if (q == 0) {
            pL_sh[s * 20 + 19]   = accH[1];
            psiL_sh[s * 20 + 19] = accH[0];
        }
    }

    __syncthreads();

    // ---- epilogue: sigmoid + oxy, coalesced ----
    const float wpo = W_p[HDIM];
    // psi0
    if (lane < 16) out_psi0[base + lane] = sigmoidf_(psi0L_sh[lane]);
    // psi: out flat i = site_local*19 + c  <-  psiL_sh[site_local*20 + c + 1]
#pragma unroll
    for (int r = 0; r < 5; ++r) {
        int i = r * 64 + lane;
        if (i < 16 * 19) {
            int sl = i / 19, c = i - sl * 19;
            out_psi[(size_t)base * 19 + i] = sigmoidf_(psiL_sh[sl * 20 + c + 1]);
        }
    }
    // p: 16*40 = 640 floats = 160 float4; float idx f -> logit pL_sh[f>>1]
    const float4* oxy_b = (const float4*)(oxy + (size_t)base * 40);
    float4* outp_b = (float4*)(out_p + (size_t)base * 40);
#pragma unroll
    for (int r = 0; r < 3; ++r) {
        int i4 = r * 64 + lane;
        if (i4 < 160) {
            float4 ox = oxy_b[i4];
            float lg0 = pL_sh[i4 * 2];
            float lg1 = pL_sh[i4 * 2 + 1];
            float4 pv;
            pv.x = sigmoidf_(fmaf(wpo, ox.x, lg0));
            pv.y = sigmoidf_(fmaf(wpo, ox.y, lg0));
            pv.z = sigmoidf_(fmaf(wpo, ox.z, lg1));
            pv.w = sigmoidf_(fmaf(wpo, ox.w, lg1));
            outp_b[i4] = pv;
        }
    }
}

extern "C" void kernel_launch(void* const* d_in, const int* in_sizes, int n_in,
                              void* d_out, int out_size, void* d_ws, size_t ws_size,
                              hipStream_t stream) {
    const float* sxy0   = (const float*)d_in[0];
    const float* sxy    = (const float*)d_in[1];
    const float* oxy    = (const float*)d_in[2];
    const float* W_h0   = (const float*)d_in[3];
    const float* b_h0   = (const float*)d_in[4];
    const float* W_h1   = (const float*)d_in[5];
    const float* b_h1   = (const float*)d_in[6];
    const float* W_ih   = (const float*)d_in[7];
    const float* b_ih   = (const float*)d_in[8];
    const float* W_hh   = (const float*)d_in[9];
    const float* b_hh   = (const float*)d_in[10];
    const float* W_psi0 = (const float*)d_in[11];
    const float* b_psi0 = (const float*)d_in[12];
    const float* W_psi  = (const float*)d_in[13];
    const float* b_psi  = (const float*)d_in[14];
    const float* W_p    = (const float*)d_in[15];
    const float* b_p    = (const float*)d_in[16];

    float* out = (float*)d_out;

    dim3 block(64);
    dim3 grid(NSITES / 16);   // 6250 waves, 16 sites each
    rnet_kernel<<<grid, block, 0, stream>>>(
        sxy0, sxy, oxy, W_h0, b_h0, W_h1, b_h1, W_ih, b_ih, W_hh, b_hh,
        W_psi0, b_psi0, W_psi, b_psi, W_p, b_p, out);
}